// Round 12
// baseline (95.723 us; speedup 1.0000x reference)
//
#include <hip/hip_runtime.h>
#include <hip/hip_fp16.h>

typedef __fp16 h2_t __attribute__((ext_vector_type(2)));
typedef _Float16 f16x8 __attribute__((ext_vector_type(8)));
typedef float f32x4 __attribute__((ext_vector_type(4)));
typedef unsigned int uint32;

#define S_DIM 8192
#define B_DIM 8192
#define Q_DIM 64
#define A_DIM 1024
#define H_DIM 64
#define N_GATES 576

#define MT 64                  // rows per block
#define KSPLIT 8
#define KC (S_DIM / KSPLIT)    // 1024 k per block
#define BK 64                  // k per staged step (256 B per row)
#define NSTEP (KC / BK)        // 16
#define NCHUNK 4
#define CHUNK (N_GATES / NCHUNK)   // 144

__device__ __forceinline__ uint32 pk_f16(float x, float y) {
    h2_t h = __builtin_amdgcn_cvt_pkrtz(x, y);
    return __builtin_bit_cast(uint32, h);
}

__device__ __forceinline__ f32x4 mfma16(uint4 a, uint4 b, f32x4 c) {
    return __builtin_amdgcn_mfma_f32_16x16x32_f16(
        __builtin_bit_cast(f16x8, a), __builtin_bit_cast(f16x8, b), c, 0, 0, 0);
}

// 16-B global->LDS DMA (no VGPR round trip); lds must be wave-uniform base,
// HW scatters lane i to base + i*16.
__device__ __forceinline__ void gload_lds16(const float* g, float* lds) {
    __builtin_amdgcn_global_load_lds(
        (const __attribute__((address_space(1))) void*)g,
        (__attribute__((address_space(3))) void*)lds, 16, 0, 0);
}

// k_pre: one launch for all input-only prep.
//  blocks [0,256):  pack enc_w -> MFMA B-fragment order f16 (r3-verified)
//  blocks [256,320): WM[j][i] = sum_a w1[j][a] * mo[a][2i]  (f-independent fold)
__global__ void k_pre(const float* __restrict__ encw, uint4* __restrict__ bpack,
                      const float* __restrict__ w1, const float* __restrict__ mo,
                      float* __restrict__ WM) {
    const int bid = blockIdx.x;
    const int t   = threadIdx.x;
    if (bid < 256) {
        const int gid  = bid * 256 + t;                 // 65536 total
        const int lane = gid & 63;
        const int nt   = (gid >> 6) & 3;
        const int kt   = gid >> 8;                      // 0..255
        const int n = nt * 16 + (lane & 15);
        const int k = kt * 32 + (lane >> 4) * 8;
        const float* p = encw + (size_t)n * S_DIM + k;
        float4 x0 = *(const float4*)p;
        float4 x1 = *(const float4*)(p + 4);
        uint4 r;
        r.x = pk_f16(x0.x, x0.y);
        r.y = pk_f16(x0.z, x0.w);
        r.z = pk_f16(x1.x, x1.y);
        r.w = pk_f16(x1.z, x1.w);
        bpack[gid] = r;
    } else {
        __shared__ float red[4][64];
        const int j    = bid - 256;                     // 0..63
        const int lane = t & 63;
        const int wv   = t >> 6;                        // 0..3
        const float* w1r = w1 + (size_t)j * A_DIM + wv * 256;
        const float* mop = mo + (size_t)wv * 256 * 128 + lane * 2;
        float acc = 0.f;
        for (int a = 0; a < 256; ++a)
            acc = fmaf(w1r[a], mop[(size_t)a * 128], acc);
        red[wv][lane] = acc;
        __syncthreads();
        if (t < 64)
            WM[(size_t)j * 64 + t] = red[0][t] + red[1][t] + red[2][t] + red[3][t];
    }
}

// K1: partial[ks][m][n] = state[m,kr].enc_w[n,kr].
// A staged via global_load_lds DMA (f32 in LDS, cvt on read), 16-B-slot XOR
// swizzle applied to BOTH the global source and the LDS read (rule #21).
// One raw barrier per step; counted vmcnt keeps next-step DMA in flight.
__global__ __launch_bounds__(256, 4) void k_gemm(
        const float* __restrict__ state, const uint4* __restrict__ bpack,
        float* __restrict__ partial) {
    __shared__ __align__(16) float As[2][MT * BK];      // 2 x 16 KB
    const int t  = threadIdx.x;
    const int w  = t >> 6;
    const int l  = t & 63;
    const int m0 = blockIdx.x * MT;
    const int ks = blockIdx.y;
    const int k0 = ks * KC;

    const uint4* pb = bpack + (size_t)(k0 >> 5) * 4 * 64 + l;

    // compute-side coords (HW-validated A-frag mapping)
    const int fr = w * 16 + (l & 15);    // row in tile
    const int g2 = l >> 4;               // k-group
    const int fx = fr & 15;              // read-side swizzle key

    // DMA staging: wave w, call i covers rows (w*4+i)*4 .. +4 (1 KB each);
    // lane l -> row +(l>>4), 16-B slot (l&15); source slot = (l&15)^(row&15).
#define DMA(BUF, S) do { \
        _Pragma("unroll") \
        for (int i = 0; i < 4; ++i) { \
            const int rl = (w * 4 + i) * 4 + (l >> 4); \
            const int ss = (l & 15) ^ (rl & 15); \
            const float* gp = state + (size_t)(m0 + rl) * S_DIM + k0 + (S) * BK + ss * 4; \
            gload_lds16(gp, &As[BUF][(w * 4 + i) * 256]); \
        } } while (0)

    f32x4 acc[4] = {};

    DMA(0, 0);   // prologue: step 0 in flight

    for (int s = 0; s < NSTEP; ++s) {
        const int cur = s & 1;
        uint4 bf0[4], bf1[4];
#pragma unroll
        for (int nt = 0; nt < 4; ++nt) {
            bf0[nt] = pb[(size_t)((s * 2 + 0) * 4 + nt) * 64];
            bf1[nt] = pb[(size_t)((s * 2 + 1) * 4 + nt) * 64];
        }
        // own 4 DMAs for As[cur] complete; the 8 B loads may stay in flight
        asm volatile("s_waitcnt vmcnt(8)" ::: "memory");
        __builtin_amdgcn_s_barrier();           // all waves' DMAs landed; prev reads done
        __builtin_amdgcn_sched_barrier(0);
        if (s + 1 < NSTEP) DMA(cur ^ 1, s + 1); // next step's DMA, crosses MFMA phase
        // swizzled LDS reads (2-way bank aliasing only) + cvt + MFMA
        const int b0 = fr * BK;
        const float4 f00 = *(const float4*)&As[cur][b0 + (((2 * g2 + 0) ^ fx) << 2)];
        const float4 f01 = *(const float4*)&As[cur][b0 + (((2 * g2 + 1) ^ fx) << 2)];
        const float4 f10 = *(const float4*)&As[cur][b0 + (((8 + 2 * g2 + 0) ^ fx) << 2)];
        const float4 f11 = *(const float4*)&As[cur][b0 + (((8 + 2 * g2 + 1) ^ fx) << 2)];
        uint4 af0, af1;
        af0.x = pk_f16(f00.x, f00.y); af0.y = pk_f16(f00.z, f00.w);
        af0.z = pk_f16(f01.x, f01.y); af0.w = pk_f16(f01.z, f01.w);
        af1.x = pk_f16(f10.x, f10.y); af1.y = pk_f16(f10.z, f10.w);
        af1.z = pk_f16(f11.x, f11.y); af1.w = pk_f16(f11.z, f11.w);
#pragma unroll
        for (int nt = 0; nt < 4; ++nt) {
            acc[nt] = mfma16(af0, bf0[nt], acc[nt]);
            acc[nt] = mfma16(af1, bf1[nt], acc[nt]);
        }
    }
#undef DMA

    // C/D: col = lane&15, row = (lane>>4)*4 + reg  (verified mapping)
    float* pc = partial + (size_t)ks * (B_DIM * Q_DIM);
    const int mr = m0 + w * 16 + (l >> 4) * 4;
    const int nc = l & 15;
#pragma unroll
    for (int nt = 0; nt < 4; ++nt)
#pragma unroll
        for (int r = 0; r < 4; ++r)
            pc[(size_t)(mr + r) * Q_DIM + nt * 16 + nc] = acc[nt][r];
}

// K2: sum partials + bias; softmax over q; per-block column sums
__global__ void k_softmax(const float* __restrict__ partial,
                          const float* __restrict__ encb,
                          float* __restrict__ colsum_parts) {
    __shared__ float red[4][64];
    const int lane = threadIdx.x & 63;
    const int wv   = threadIdx.x >> 6;
    const float eb = encb[lane];
    float accq = 0.f;
    for (int i = 0; i < 8; ++i) {
        const int r = blockIdx.x * 32 + i * 4 + wv;
        float x = eb;
#pragma unroll
        for (int ks = 0; ks < KSPLIT; ++ks)
            x += partial[(size_t)ks * (B_DIM * Q_DIM) + (size_t)r * Q_DIM + lane];
        float m = x;
        for (int o = 32; o > 0; o >>= 1) m = fmaxf(m, __shfl_xor(m, o));
        float e = __expf(x - m);
        float s = e;
        for (int o = 32; o > 0; o >>= 1) s += __shfl_xor(s, o);
        accq += e / s;
    }
    red[wv][lane] = accq;
    __syncthreads();
    if (threadIdx.x < 64) {
        colsum_parts[blockIdx.x * 64 + lane] =
            red[0][lane] + red[1][lane] + red[2][lane] + red[3][lane];
    }
}

// k_final: 256 blocks; each block redundantly: reduce t0, gate filter f (chunked
// polys + conv tree), g = conv(f,t0), h = relu(WM@g+b1), then its 4 out rows.
__global__ void k_final(const float* __restrict__ colsum_parts,
                        const float* __restrict__ qp,
                        const float* __restrict__ WM,
                        const float* __restrict__ b1,
                        const float* __restrict__ w2, const float* __restrict__ b2,
                        float* __restrict__ out) {
    __shared__ float red[4][64];
    __shared__ float t0[64];
    __shared__ float cs[N_GATES], ss[N_GATES];
    __shared__ float pA[NCHUNK][64];
    __shared__ float pB[2][64];
    __shared__ float fv[64];
    __shared__ float gv[64];
    __shared__ float hl[64];
    const int t    = threadIdx.x;          // 256
    const int lane = t & 63;
    const int wv   = t >> 6;               // 0..3

    for (int g = t; g < N_GATES; g += 256) {
        float th = qp[g] * 0.5f;
        cs[g] = __cosf(th);
        ss[g] = __sinf(th);
    }
    {
        float c = 0.f;
#pragma unroll
        for (int i = 0; i < 64; ++i)
            c += colsum_parts[(size_t)(wv * 64 + i) * 64 + lane];
        red[wv][lane] = c;
    }
    __syncthreads();
    if (t < 64)
        t0[t] = red[0][t] + red[1][t] + red[2][t] + red[3][t];
    // chunk polynomials (cs/ss ready after the sync above)
    {
        float p = (lane == 0) ? 1.f : 0.f;
        const int g0 = wv * CHUNK;
        for (int g = 0; g < CHUNK; ++g) {
            float prev = __shfl(p, (lane + 63) & 63);
            p = fmaf(cs[g0 + g], p, ss[g0 + g] * prev);
        }
        pA[wv][lane] = p;
    }
    __syncthreads();
    if (wv < 2) {
        float r = 0.f;
        for (int i = 0; i < 64; ++i)
            r += pA[2 * wv][i] * pA[2 * wv + 1][(lane - i) & 63];
        pB[wv][lane] = r;
    }
    __syncthreads();
    if (wv == 0) {
        float r = 0.f;
        for (int i = 0; i < 64; ++i)
            r += pB[0][i] * pB[1][(lane - i) & 63];
        fv[lane] = r;
    }
    __syncthreads();
    if (wv == 0) {
        float r = 0.f;
        for (int i = 0; i < 64; ++i)
            r += fv[i] * t0[(lane - i) & 63];
        gv[lane] = r;
    }
    __syncthreads();
    if (t < 64) {
        float v = 0.f;
        const float* wr = WM + (size_t)t * 64;
#pragma unroll
        for (int q = 0; q < 64; ++q)
            v = fmaf(wr[q], gv[q], v);
        hl[t] = fmaxf(v + b1[t], 0.f);
    }
    __syncthreads();
    const int a = blockIdx.x * 4 + wv;
    float v = w2[(size_t)a * H_DIM + lane] * hl[lane];
    for (int o = 32; o > 0; o >>= 1) v += __shfl_xor(v, o);
    if (lane == 0) out[a] = v + b2[a];
}

extern "C" void kernel_launch(void* const* d_in, const int* in_sizes, int n_in,
                              void* d_out, int out_size, void* d_ws, size_t ws_size,
                              hipStream_t stream) {
    const float* state = (const float*)d_in[0];
    const float* encw  = (const float*)d_in[1];
    const float* encb  = (const float*)d_in[2];
    const float* qp    = (const float*)d_in[3];
    const float* mo    = (const float*)d_in[4];
    const float* w1    = (const float*)d_in[5];
    const float* b1    = (const float*)d_in[6];
    const float* w2    = (const float*)d_in[7];
    const float* b2    = (const float*)d_in[8];
    float* out = (float*)d_out;

    float* ws           = (float*)d_ws;
    float* colsum_parts = ws;                              // 16384 floats
    float* partial      = ws + 16384;                      // 8*524288 (16 MB)
    float* WM           = partial + (size_t)KSPLIT * B_DIM * Q_DIM;  // 4096
    uint4* bpack        = (uint4*)(WM + 4096);             // 65536 uint4 (1 MB)

    k_pre<<<dim3(320), dim3(256), 0, stream>>>(encw, bpack, w1, mo, WM);
    k_gemm<<<dim3(B_DIM / MT, KSPLIT), dim3(256), 0, stream>>>(state, bpack, partial);
    k_softmax<<<dim3(256), dim3(256), 0, stream>>>(partial, encb, colsum_parts);
    k_final<<<dim3(256), dim3(256), 0, stream>>>(colsum_parts, qp, WM, b1, w2, b2, out);
}